// Round 9
// baseline (134.645 us; speedup 1.0000x reference)
//
#include <hip/hip_runtime.h>
#include <hip/hip_bf16.h>

#define N_ATOMS 512
#define CDIM 64
#define NSIG 16384
#define KS 4
#define NBINS 33
#define NS_BLK 16   // signals per fused block (4 waves x 4 signals)

// ws layout (floats): [0,32768) Dn[c][n] ; [32768,65536) DnT[n][c] ;
// [65536,327680) G[n][n] ; [327680,344064) per-signal loss partials
#define WS_DN   0
#define WS_DNT  32768
#define WS_G    65536
#define WS_PART 327680

__global__ void k_normalize(const float* __restrict__ dict,
                            float* __restrict__ Dn, float* __restrict__ DnT) {
    const int n = blockIdx.x;    // atom/column
    const int c = threadIdx.x;   // channel/row (64 threads = 1 wave)
    float v = dict[c * N_ATOMS + n];
    float sq = v * v;
    #pragma unroll
    for (int off = 32; off > 0; off >>= 1) sq += __shfl_down(sq, off);
    sq = __shfl(sq, 0);
    float m = fmaxf(sqrtf(sq), 1e-10f);
    float r = v / m;             // division to match reference exactly
    Dn[c * N_ATOMS + n] = r;
    DnT[n * CDIM + c]  = r;
}

__global__ void k_gram(const float* __restrict__ Dn, float* __restrict__ G) {
    __shared__ float sc[CDIM];
    const int i = blockIdx.x;
    const int t = threadIdx.x;
    if (t < CDIM) sc[t] = Dn[t * N_ATOMS + i];
    __syncthreads();
    for (int j = t; j < N_ATOMS; j += 256) {
        float a = 0.f;
        #pragma unroll
        for (int c = 0; c < CDIM; c++) a = fmaf(sc[c], Dn[c * N_ATOMS + j], a);
        G[i * N_ATOMS + j] = a;
    }
}

__device__ __forceinline__ float pick8(const float* a, int s) {
    switch (s) {
        case 0: return a[0]; case 1: return a[1]; case 2: return a[2]; case 3: return a[3];
        case 4: return a[4]; case 5: return a[5]; case 6: return a[6]; default: return a[7];
    }
}

// OMP body with G-row register caching: row I[k] loaded ONCE at selection,
// Cholesky column scalars come from cached rows via shfl (no loads on chain).
// All arithmetic values/order bit-identical to the previous omp_body.
__device__ __forceinline__ void omp_body(
    const float hb[8], const float* __restrict__ G, int lane,
    int I[KS], float coef[KS])
{
    float h[8];
    #pragma unroll
    for (int j = 0; j < 8; j++) h[j] = hb[j];

    unsigned sel = 0;
    float L[KS][KS];
    float hsel[KS];
    float grow[KS - 1][8];   // cached G rows for I[0..2] (lane's 8-atom slice)
    L[0][0] = 1.f;

    #pragma unroll
    for (int k = 0; k < KS; k++) {
        // argmax of |where(selected, 0, h)|, first-max tie-break (lowest atom idx)
        float bv = -1.f; int bn = N_ATOMS;
        #pragma unroll
        for (int j = 0; j < 8; j++) {
            float v = (sel & (1u << j)) ? 0.f : fabsf(h[j]);
            if (v > bv) { bv = v; bn = lane * 8 + j; }
        }
        #pragma unroll
        for (int off = 32; off > 0; off >>= 1) {
            float ov = __shfl_down(bv, off);
            int   on = __shfl_down(bn, off);
            if (ov > bv || (ov == bv && on < bn)) { bv = ov; bn = on; }
        }
        const int idx = __shfl(bn, 0);
        if ((idx >> 3) == lane) sel |= 1u << (idx & 7);

        // issue the (single) new G-row load immediately; consumed by the
        // h-update below, overlapping the load with the solve chain
        if (k < KS - 1) {
            const float4* gr = (const float4*)(G + idx * N_ATOMS + lane * 8);
            float4 g0 = gr[0], g1 = gr[1];
            grow[k][0] = g0.x; grow[k][1] = g0.y; grow[k][2] = g0.z; grow[k][3] = g0.w;
            grow[k][4] = g1.x; grow[k][5] = g1.y; grow[k][6] = g1.z; grow[k][7] = g1.w;
        }

        if (k > 0) {
            // G[I[i2]][idx] from cached rows via shfl (identical bits)
            float gcol[KS - 1];
            #pragma unroll
            for (int i2 = 0; i2 < KS - 1; i2++) {
                if (i2 < k)
                    gcol[i2] = __shfl(pick8(grow[i2], idx & 7), idx >> 3);
            }
            float w[KS - 1];
            for (int i2 = 0; i2 < k; i2++) {
                float t = gcol[i2];
                for (int j2 = 0; j2 < i2; j2++) t -= L[i2][j2] * w[j2];
                w[i2] = t / L[i2][i2];
            }
            float ssum = 0.f;
            for (int j2 = 0; j2 < k; j2++) ssum += w[j2] * w[j2];
            float corner = sqrtf(fmaxf(1.f - ssum, 1e-12f));
            for (int j2 = 0; j2 < k; j2++) L[k][j2] = w[j2];
            L[k][k] = corner;
        }
        I[k] = idx;
        hsel[k] = __shfl(pick8(hb, idx & 7), idx >> 3);

        float y[KS];
        for (int i2 = 0; i2 <= k; i2++) {
            float t = hsel[i2];
            for (int j2 = 0; j2 < i2; j2++) t -= L[i2][j2] * y[j2];
            y[i2] = t / L[i2][i2];
        }
        for (int i2 = k; i2 >= 0; i2--) {
            float t = y[i2];
            for (int j2 = i2 + 1; j2 <= k; j2++) t -= L[j2][i2] * coef[j2];
            coef[i2] = t / L[i2][i2];
        }

        // h = h_bar - x @ G from cached rows (same fmaf order as before)
        if (k < KS - 1) {
            float a[8];
            #pragma unroll
            for (int j = 0; j < 8; j++) a[j] = 0.f;
            for (int m = 0; m <= k; m++) {
                float cm = coef[m];
                #pragma unroll
                for (int j = 0; j < 8; j++)
                    a[j] = fmaf(cm, grow[m][j], a[j]);
            }
            #pragma unroll
            for (int j = 0; j < 8; j++) h[j] = hb[j] - a[j];
        }
    }
}

// Fused v2: wave-partitioned GEMM (hb in registers) + OMP. LDS ~9 KB.
__global__ __launch_bounds__(256) void k_fused2(
    const float* __restrict__ z, const float* __restrict__ Dn,
    const float* __restrict__ DnT, const float* __restrict__ G,
    float* __restrict__ part, float* __restrict__ out)
{
    __shared__ float Xs[CDIM][NS_BLK + 1];  // [c][s]
    __shared__ float zo[CDIM][NS_BLK + 1];  // zste staging [c][s]
    __shared__ float tk[NS_BLK][4];
    const int t = threadIdx.x;
    const int wave = t >> 6, lane = t & 63;
    const int s0 = blockIdx.x * NS_BLK;
    const int b = s0 >> 10;
    const int hw0 = s0 & 1023;

    {   // coalesced z stage: thread t -> channel c = t>>2, signals f..f+3
        const int c = t >> 2, f = (t & 3) * 4;
        float4 v = *(const float4*)(z + (b * CDIM + c) * 1024 + hw0 + f);
        Xs[c][f + 0] = v.x; Xs[c][f + 1] = v.y;
        Xs[c][f + 2] = v.z; Xs[c][f + 3] = v.w;
    }
    __syncthreads();

    // GEMM: wave owns signals wave*4..+3; lane owns atoms lane*8..+7.
    float hb4[4][8];
    #pragma unroll
    for (int q = 0; q < 4; q++)
        #pragma unroll
        for (int j = 0; j < 8; j++) hb4[q][j] = 0.f;

    for (int k = 0; k < CDIM; k++) {
        const float4* dp = (const float4*)(Dn + k * N_ATOMS + lane * 8);
        float4 d0 = dp[0], d1 = dp[1];
        #pragma unroll
        for (int q = 0; q < 4; q++) {
            const float x = Xs[k][wave * 4 + q];   // wave-uniform broadcast
            hb4[q][0] = fmaf(x, d0.x, hb4[q][0]);
            hb4[q][1] = fmaf(x, d0.y, hb4[q][1]);
            hb4[q][2] = fmaf(x, d0.z, hb4[q][2]);
            hb4[q][3] = fmaf(x, d0.w, hb4[q][3]);
            hb4[q][4] = fmaf(x, d1.x, hb4[q][4]);
            hb4[q][5] = fmaf(x, d1.y, hb4[q][5]);
            hb4[q][6] = fmaf(x, d1.z, hb4[q][6]);
            hb4[q][7] = fmaf(x, d1.w, hb4[q][7]);
        }
    }

    // OMP + epilogue for the wave's 4 signals
    #pragma unroll 1
    for (int q = 0; q < 4; q++) {
        const int sl = wave * 4 + q;
        const int s = s0 + sl;
        const float xch = Xs[lane][sl];

        int I[KS]; float coef[KS];
        omp_body(hb4[q], G, lane, I, coef);

        int tok[KS]; float cq[KS];
        #pragma unroll
        for (int j = 0; j < KS; j++) {
            float c2 = fminf(fmaxf(coef[j], -2.f), 2.f);
            float bf = (c2 + 2.f) / 4.f * 32.f;
            int bin = (int)rintf(bf);
            bin = bin < 0 ? 0 : (bin > 32 ? 32 : bin);
            cq[j] = -2.f + 0.125f * (float)bin;
            tok[j] = I[j] * NBINS + bin;
        }
        float zq = 0.f;
        #pragma unroll
        for (int j = 0; j < KS; j++)
            zq = fmaf(cq[j], DnT[I[j] * CDIM + lane], zq);

        float diff = zq - xch;
        zo[lane][sl] = xch + (zq - xch);   // STE

        float sq = diff * diff;
        #pragma unroll
        for (int off = 32; off > 0; off >>= 1) sq += __shfl_down(sq, off);
        if (lane == 0) part[s] = sq;
        if (lane < KS) tk[sl][lane] = (float)tok[lane];
    }
    __syncthreads();

    {   // coalesced zste write
        const int c = t >> 2, f = (t & 3) * 4;
        float4 v;
        v.x = zo[c][f + 0]; v.y = zo[c][f + 1];
        v.z = zo[c][f + 2]; v.w = zo[c][f + 3];
        *(float4*)(out + (b * CDIM + c) * 1024 + hw0 + f) = v;
    }
    if (t < NS_BLK * KS)   // 64 consecutive token floats
        out[NSIG * CDIM + 1 + s0 * KS + t] = tk[t >> 2][t & 3];
}

__global__ __launch_bounds__(256) void k_final(const float* __restrict__ part,
                                               float* __restrict__ out) {
    __shared__ float red[4];
    const int t = threadIdx.x;
    float sum = 0.f;
    const float4* p4 = (const float4*)part;
    for (int i = t; i < NSIG / 4; i += 256) {
        float4 v = p4[i];
        sum += v.x + v.y + v.z + v.w;
    }
    #pragma unroll
    for (int off = 32; off > 0; off >>= 1) sum += __shfl_down(sum, off);
    if ((t & 63) == 0) red[t >> 6] = sum;
    __syncthreads();
    if (t == 0) {
        float v = (red[0] + red[1] + red[2] + red[3]) / 1048576.f;
        out[NSIG * CDIM] = v + 0.25f * v;
    }
}

extern "C" void kernel_launch(void* const* d_in, const int* in_sizes, int n_in,
                              void* d_out, int out_size, void* d_ws, size_t ws_size,
                              hipStream_t stream) {
    const float* z    = (const float*)d_in[0];
    const float* dict = (const float*)d_in[1];
    float* out  = (float*)d_out;
    float* w    = (float*)d_ws;
    float* Dn   = w + WS_DN;
    float* DnT  = w + WS_DNT;
    float* G    = w + WS_G;
    float* part = w + WS_PART;

    hipLaunchKernelGGL(k_normalize, dim3(N_ATOMS), dim3(CDIM), 0, stream, dict, Dn, DnT);
    hipLaunchKernelGGL(k_gram,      dim3(N_ATOMS), dim3(256),  0, stream, Dn, G);
    hipLaunchKernelGGL(k_fused2,    dim3(NSIG / NS_BLK), dim3(256), 0, stream,
                       z, Dn, DnT, G, part, out);
    hipLaunchKernelGGL(k_final,     dim3(1), dim3(256), 0, stream, part, out);
}

// Round 10
// 123.674 us; speedup vs baseline: 1.0887x; 1.0887x over previous
//
#include <hip/hip_runtime.h>
#include <hip/hip_bf16.h>

#define N_ATOMS 512
#define CDIM 64
#define NSIG 16384
#define KS 4
#define NBINS 33
#define NS_BLK 8    // signals per fused block (4 waves; wave = 128 atoms in GEMM, 2 signals in OMP)

// ws layout (floats): [0,32768) Dn[c][n] ; [32768,65536) DnT[n][c] ;
// [65536,327680) G[n][n] ; [327680,344064) per-signal loss partials
#define WS_DN   0
#define WS_DNT  32768
#define WS_G    65536
#define WS_PART 327680

__global__ void k_normalize(const float* __restrict__ dict,
                            float* __restrict__ Dn, float* __restrict__ DnT) {
    const int n = blockIdx.x;    // atom/column
    const int c = threadIdx.x;   // channel/row (64 threads = 1 wave)
    float v = dict[c * N_ATOMS + n];
    float sq = v * v;
    #pragma unroll
    for (int off = 32; off > 0; off >>= 1) sq += __shfl_down(sq, off);
    sq = __shfl(sq, 0);
    float m = fmaxf(sqrtf(sq), 1e-10f);
    float r = v / m;             // division to match reference exactly
    Dn[c * N_ATOMS + n] = r;
    DnT[n * CDIM + c]  = r;
}

__global__ void k_gram(const float* __restrict__ Dn, float* __restrict__ G) {
    __shared__ float sc[CDIM];
    const int i = blockIdx.x;
    const int t = threadIdx.x;
    if (t < CDIM) sc[t] = Dn[t * N_ATOMS + i];
    __syncthreads();
    for (int j = t; j < N_ATOMS; j += 256) {
        float a = 0.f;
        #pragma unroll
        for (int c = 0; c < CDIM; c++) a = fmaf(sc[c], Dn[c * N_ATOMS + j], a);
        G[i * N_ATOMS + j] = a;
    }
}

__device__ __forceinline__ float pick8(const float* a, int s) {
    switch (s) {
        case 0: return a[0]; case 1: return a[1]; case 2: return a[2]; case 3: return a[3];
        case 4: return a[4]; case 5: return a[5]; case 6: return a[6]; default: return a[7];
    }
}

// Round-8 omp_body (global G loads): values/order bit-identical to all passing rounds.
__device__ __forceinline__ void omp_body(
    const float hb[8], const float* __restrict__ G, int lane,
    int I[KS], float coef[KS])
{
    float h[8];
    #pragma unroll
    for (int j = 0; j < 8; j++) h[j] = hb[j];

    unsigned sel = 0;
    float L[KS][KS];
    float hsel[KS];
    L[0][0] = 1.f;

    #pragma unroll
    for (int k = 0; k < KS; k++) {
        float bv = -1.f; int bn = N_ATOMS;
        #pragma unroll
        for (int j = 0; j < 8; j++) {
            float v = (sel & (1u << j)) ? 0.f : fabsf(h[j]);
            if (v > bv) { bv = v; bn = lane * 8 + j; }
        }
        #pragma unroll
        for (int off = 32; off > 0; off >>= 1) {
            float ov = __shfl_down(bv, off);
            int   on = __shfl_down(bn, off);
            if (ov > bv || (ov == bv && on < bn)) { bv = ov; bn = on; }
        }
        const int idx = __shfl(bn, 0);
        if ((idx >> 3) == lane) sel |= 1u << (idx & 7);

        if (k > 0) {
            float w[KS - 1];
            for (int i2 = 0; i2 < k; i2++) {
                float t = G[I[i2] * N_ATOMS + idx];
                for (int j2 = 0; j2 < i2; j2++) t -= L[i2][j2] * w[j2];
                w[i2] = t / L[i2][i2];
            }
            float ssum = 0.f;
            for (int j2 = 0; j2 < k; j2++) ssum += w[j2] * w[j2];
            float corner = sqrtf(fmaxf(1.f - ssum, 1e-12f));
            for (int j2 = 0; j2 < k; j2++) L[k][j2] = w[j2];
            L[k][k] = corner;
        }
        I[k] = idx;
        hsel[k] = __shfl(pick8(hb, idx & 7), idx >> 3);

        float y[KS];
        for (int i2 = 0; i2 <= k; i2++) {
            float t = hsel[i2];
            for (int j2 = 0; j2 < i2; j2++) t -= L[i2][j2] * y[j2];
            y[i2] = t / L[i2][i2];
        }
        for (int i2 = k; i2 >= 0; i2--) {
            float t = y[i2];
            for (int j2 = i2 + 1; j2 <= k; j2++) t -= L[j2][i2] * coef[j2];
            coef[i2] = t / L[i2][i2];
        }

        if (k < KS - 1) {
            float a[8];
            #pragma unroll
            for (int j = 0; j < 8; j++) a[j] = 0.f;
            for (int m = 0; m <= k; m++) {
                const float4* gr = (const float4*)(G + I[m] * N_ATOMS + lane * 8);
                float4 g0 = gr[0], g1 = gr[1];
                float cm = coef[m];
                a[0] = fmaf(cm, g0.x, a[0]); a[1] = fmaf(cm, g0.y, a[1]);
                a[2] = fmaf(cm, g0.z, a[2]); a[3] = fmaf(cm, g0.w, a[3]);
                a[4] = fmaf(cm, g1.x, a[4]); a[5] = fmaf(cm, g1.y, a[5]);
                a[6] = fmaf(cm, g1.z, a[6]); a[7] = fmaf(cm, g1.w, a[7]);
            }
            #pragma unroll
            for (int j = 0; j < 8; j++) h[j] = hb[j] - a[j];
        }
    }
}

// Fused v3: 8 signals/block, atom-split GEMM through LDS, 2 OMP signals/wave.
__global__ __launch_bounds__(256, 8) void k_fused3(
    const float* __restrict__ z, const float* __restrict__ Dn,
    const float* __restrict__ DnT, const float* __restrict__ G,
    float* __restrict__ part, float* __restrict__ out)
{
    __shared__ float Xs[CDIM][NS_BLK];      // [c][s] 2 KB
    __shared__ float Hs[NS_BLK][516];       // hbar tile 16.5 KB; reused for zste
    __shared__ float tk[NS_BLK][4];
    const int t = threadIdx.x;
    const int wave = t >> 6, lane = t & 63;
    const int s0 = blockIdx.x * NS_BLK;
    const int b = s0 >> 10;
    const int hw0 = s0 & 1023;

    if (t < 128) {   // coalesced z stage: c = t>>1, signals f..f+3 (f = (t&1)*4)
        const int c = t >> 1, f = (t & 1) * 4;
        float4 v = *(const float4*)(z + (b * CDIM + c) * 1024 + hw0 + f);
        Xs[c][f + 0] = v.x; Xs[c][f + 1] = v.y;
        Xs[c][f + 2] = v.z; Xs[c][f + 3] = v.w;
    }
    __syncthreads();

    {   // GEMM: wave owns atoms [wave*128, +128); lane owns 2 atoms.
        // k-ascending fmaf per (signal, atom) — bit-identical to prior rounds.
        const int n0 = wave * 128 + lane * 2;
        float acc[NS_BLK][2];
        #pragma unroll
        for (int q = 0; q < NS_BLK; q++) { acc[q][0] = 0.f; acc[q][1] = 0.f; }
        for (int k = 0; k < CDIM; k++) {
            const float2 d = *(const float2*)(Dn + k * N_ATOMS + n0);
            float4 xlo = *(const float4*)(&Xs[k][0]);
            float4 xhi = *(const float4*)(&Xs[k][4]);
            const float xs[NS_BLK] = {xlo.x, xlo.y, xlo.z, xlo.w,
                                      xhi.x, xhi.y, xhi.z, xhi.w};
            #pragma unroll
            for (int q = 0; q < NS_BLK; q++) {
                acc[q][0] = fmaf(xs[q], d.x, acc[q][0]);
                acc[q][1] = fmaf(xs[q], d.y, acc[q][1]);
            }
        }
        #pragma unroll
        for (int q = 0; q < NS_BLK; q++)
            *(float2*)(&Hs[q][n0]) = make_float2(acc[q][0], acc[q][1]);
    }
    __syncthreads();

    // OMP: wave handles 2 signals sequentially; hb from LDS.
    #pragma unroll 1
    for (int q = 0; q < 2; q++) {
        const int sl = wave * 2 + q;
        const int s = s0 + sl;
        const float xch = Xs[lane][sl];

        float hb[8];
        *(float4*)(&hb[0]) = *(const float4*)(&Hs[sl][lane * 8]);
        *(float4*)(&hb[4]) = *(const float4*)(&Hs[sl][lane * 8 + 4]);

        int I[KS]; float coef[KS];
        omp_body(hb, G, lane, I, coef);

        int tok[KS]; float cq[KS];
        #pragma unroll
        for (int j = 0; j < KS; j++) {
            float c2 = fminf(fmaxf(coef[j], -2.f), 2.f);
            float bf = (c2 + 2.f) / 4.f * 32.f;
            int bin = (int)rintf(bf);
            bin = bin < 0 ? 0 : (bin > 32 ? 32 : bin);
            cq[j] = -2.f + 0.125f * (float)bin;
            tok[j] = I[j] * NBINS + bin;
        }
        float zq = 0.f;
        #pragma unroll
        for (int j = 0; j < KS; j++)
            zq = fmaf(cq[j], DnT[I[j] * CDIM + lane], zq);

        float diff = zq - xch;
        Hs[sl][lane] = xch + (zq - xch);   // zste overlay (row sl is dead now)

        float sq = diff * diff;
        #pragma unroll
        for (int off = 32; off > 0; off >>= 1) sq += __shfl_down(sq, off);
        if (lane == 0) part[s] = sq;
        if (lane < KS) tk[sl][lane] = (float)tok[lane];
    }
    __syncthreads();

    if (t < 128) {   // coalesced zste write: c = t>>1, signals f..f+3
        const int c = t >> 1, f = (t & 1) * 4;
        float4 v;
        v.x = Hs[f + 0][c]; v.y = Hs[f + 1][c];
        v.z = Hs[f + 2][c]; v.w = Hs[f + 3][c];
        *(float4*)(out + (b * CDIM + c) * 1024 + hw0 + f) = v;
    }
    if (t < NS_BLK * KS)   // 32 consecutive token floats
        out[NSIG * CDIM + 1 + s0 * KS + t] = tk[t >> 2][t & 3];
}

__global__ __launch_bounds__(256) void k_final(const float* __restrict__ part,
                                               float* __restrict__ out) {
    __shared__ float red[4];
    const int t = threadIdx.x;
    float sum = 0.f;
    const float4* p4 = (const float4*)part;
    for (int i = t; i < NSIG / 4; i += 256) {
        float4 v = p4[i];
        sum += v.x + v.y + v.z + v.w;
    }
    #pragma unroll
    for (int off = 32; off > 0; off >>= 1) sum += __shfl_down(sum, off);
    if ((t & 63) == 0) red[t >> 6] = sum;
    __syncthreads();
    if (t == 0) {
        float v = (red[0] + red[1] + red[2] + red[3]) / 1048576.f;
        out[NSIG * CDIM] = v + 0.25f * v;
    }
}

extern "C" void kernel_launch(void* const* d_in, const int* in_sizes, int n_in,
                              void* d_out, int out_size, void* d_ws, size_t ws_size,
                              hipStream_t stream) {
    const float* z    = (const float*)d_in[0];
    const float* dict = (const float*)d_in[1];
    float* out  = (float*)d_out;
    float* w    = (float*)d_ws;
    float* Dn   = w + WS_DN;
    float* DnT  = w + WS_DNT;
    float* G    = w + WS_G;
    float* part = w + WS_PART;

    hipLaunchKernelGGL(k_normalize, dim3(N_ATOMS), dim3(CDIM), 0, stream, dict, Dn, DnT);
    hipLaunchKernelGGL(k_gram,      dim3(N_ATOMS), dim3(256),  0, stream, Dn, G);
    hipLaunchKernelGGL(k_fused3,    dim3(NSIG / NS_BLK), dim3(256), 0, stream,
                       z, Dn, DnT, G, part, out);
    hipLaunchKernelGGL(k_final,     dim3(1), dim3(256), 0, stream, part, out);
}

// Round 11
// 120.528 us; speedup vs baseline: 1.1171x; 1.0261x over previous
//
#include <hip/hip_runtime.h>
#include <hip/hip_bf16.h>

#define N_ATOMS 512
#define CDIM 64
#define NSIG 16384
#define KS 4
#define NBINS 33
#define NS_BLK 8    // signals per fused block (4 waves; wave = 128 atoms in GEMM, 2 signals in OMP)

// ws layout (floats): [0,32768) Dn[c][n] ; [32768,65536) DnT[n][c] ;
// [65536,327680) G[n][n] ; [327680,344064) per-signal loss partials
#define WS_DN   0
#define WS_DNT  32768
#define WS_G    65536
#define WS_PART 327680

__global__ void k_normalize(const float* __restrict__ dict,
                            float* __restrict__ Dn, float* __restrict__ DnT) {
    const int n = blockIdx.x;    // atom/column
    const int c = threadIdx.x;   // channel/row (64 threads = 1 wave)
    float v = dict[c * N_ATOMS + n];
    float sq = v * v;
    #pragma unroll
    for (int off = 32; off > 0; off >>= 1) sq += __shfl_down(sq, off);
    sq = __shfl(sq, 0);
    float m = fmaxf(sqrtf(sq), 1e-10f);
    float r = v / m;             // division to match reference exactly
    Dn[c * N_ATOMS + n] = r;
    DnT[n * CDIM + c]  = r;
}

__global__ void k_gram(const float* __restrict__ Dn, float* __restrict__ G) {
    __shared__ float sc[CDIM];
    const int i = blockIdx.x;
    const int t = threadIdx.x;
    if (t < CDIM) sc[t] = Dn[t * N_ATOMS + i];
    __syncthreads();
    for (int j = t; j < N_ATOMS; j += 256) {
        float a = 0.f;
        #pragma unroll
        for (int c = 0; c < CDIM; c++) a = fmaf(sc[c], Dn[c * N_ATOMS + j], a);
        G[i * N_ATOMS + j] = a;
    }
}

// OMP body. hrow = this signal's h_bar row in LDS (hb[j] == hrow[lane*8+j]).
// hsel comes straight from LDS (identical bits). Triangular solves use
// reciprocal-multiply (inv[i] = 1/L[i][i], one divide per step instead of ~5;
// <=2 ulp difference on coef — selection/binning unaffected).
__device__ __forceinline__ void omp_body(
    const float hb[8], const float* hrow, const float* __restrict__ G, int lane,
    int I[KS], float coef[KS])
{
    float h[8];
    #pragma unroll
    for (int j = 0; j < 8; j++) h[j] = hb[j];

    unsigned sel = 0;
    float L[KS][KS];
    float hsel[KS];
    float inv[KS];
    L[0][0] = 1.f; inv[0] = 1.f;

    #pragma unroll
    for (int k = 0; k < KS; k++) {
        // argmax of |where(selected, 0, h)|, first-max tie-break (lowest atom idx)
        float bv = -1.f; int bn = N_ATOMS;
        #pragma unroll
        for (int j = 0; j < 8; j++) {
            float v = (sel & (1u << j)) ? 0.f : fabsf(h[j]);
            if (v > bv) { bv = v; bn = lane * 8 + j; }
        }
        #pragma unroll
        for (int off = 32; off > 0; off >>= 1) {
            float ov = __shfl_down(bv, off);
            int   on = __shfl_down(bn, off);
            if (ov > bv || (ov == bv && on < bn)) { bv = ov; bn = on; }
        }
        const int idx = __shfl(bn, 0);
        if ((idx >> 3) == lane) sel |= 1u << (idx & 7);

        if (k > 0) {
            float w[KS - 1];
            for (int i2 = 0; i2 < k; i2++) {
                float t = G[I[i2] * N_ATOMS + idx];   // wave-uniform scalar load
                for (int j2 = 0; j2 < i2; j2++) t -= L[i2][j2] * w[j2];
                w[i2] = t * inv[i2];
            }
            float ssum = 0.f;
            for (int j2 = 0; j2 < k; j2++) ssum += w[j2] * w[j2];
            float corner = sqrtf(fmaxf(1.f - ssum, 1e-12f));
            for (int j2 = 0; j2 < k; j2++) L[k][j2] = w[j2];
            L[k][k] = corner;
            inv[k] = 1.f / corner;
        }
        I[k] = idx;
        hsel[k] = hrow[idx];               // LDS broadcast read, same bits as hb

        float y[KS];
        for (int i2 = 0; i2 <= k; i2++) {
            float t = hsel[i2];
            for (int j2 = 0; j2 < i2; j2++) t -= L[i2][j2] * y[j2];
            y[i2] = t * inv[i2];
        }
        for (int i2 = k; i2 >= 0; i2--) {
            float t = y[i2];
            for (int j2 = i2 + 1; j2 <= k; j2++) t -= L[j2][i2] * coef[j2];
            coef[i2] = t * inv[i2];
        }

        if (k < KS - 1) {
            float a[8];
            #pragma unroll
            for (int j = 0; j < 8; j++) a[j] = 0.f;
            for (int m = 0; m <= k; m++) {
                const float4* gr = (const float4*)(G + I[m] * N_ATOMS + lane * 8);
                float4 g0 = gr[0], g1 = gr[1];
                float cm = coef[m];
                a[0] = fmaf(cm, g0.x, a[0]); a[1] = fmaf(cm, g0.y, a[1]);
                a[2] = fmaf(cm, g0.z, a[2]); a[3] = fmaf(cm, g0.w, a[3]);
                a[4] = fmaf(cm, g1.x, a[4]); a[5] = fmaf(cm, g1.y, a[5]);
                a[6] = fmaf(cm, g1.z, a[6]); a[7] = fmaf(cm, g1.w, a[7]);
            }
            #pragma unroll
            for (int j = 0; j < 8; j++) h[j] = hb[j] - a[j];
        }
    }
}

// Fused v4: 8 signals/block, atom-split GEMM through LDS, 2 interleaved OMP signals/wave.
__global__ __launch_bounds__(256, 8) void k_fused3(
    const float* __restrict__ z, const float* __restrict__ Dn,
    const float* __restrict__ DnT, const float* __restrict__ G,
    float* __restrict__ part, float* __restrict__ out)
{
    __shared__ float Xs[CDIM][NS_BLK];      // [c][s] 2 KB
    __shared__ float Hs[NS_BLK][516];       // hbar tile 16.5 KB; reused for zste
    __shared__ float tk[NS_BLK][4];
    const int t = threadIdx.x;
    const int wave = t >> 6, lane = t & 63;
    const int s0 = blockIdx.x * NS_BLK;
    const int b = s0 >> 10;
    const int hw0 = s0 & 1023;

    if (t < 128) {   // coalesced z stage: c = t>>1, signals f..f+3 (f = (t&1)*4)
        const int c = t >> 1, f = (t & 1) * 4;
        float4 v = *(const float4*)(z + (b * CDIM + c) * 1024 + hw0 + f);
        Xs[c][f + 0] = v.x; Xs[c][f + 1] = v.y;
        Xs[c][f + 2] = v.z; Xs[c][f + 3] = v.w;
    }
    __syncthreads();

    {   // GEMM: wave owns atoms [wave*128, +128); lane owns 2 atoms.
        // k-ascending fmaf per (signal, atom) — bit-identical to prior rounds.
        const int n0 = wave * 128 + lane * 2;
        float acc[NS_BLK][2];
        #pragma unroll
        for (int q = 0; q < NS_BLK; q++) { acc[q][0] = 0.f; acc[q][1] = 0.f; }
        for (int k = 0; k < CDIM; k++) {
            const float2 d = *(const float2*)(Dn + k * N_ATOMS + n0);
            float4 xlo = *(const float4*)(&Xs[k][0]);
            float4 xhi = *(const float4*)(&Xs[k][4]);
            const float xs[NS_BLK] = {xlo.x, xlo.y, xlo.z, xlo.w,
                                      xhi.x, xhi.y, xhi.z, xhi.w};
            #pragma unroll
            for (int q = 0; q < NS_BLK; q++) {
                acc[q][0] = fmaf(xs[q], d.x, acc[q][0]);
                acc[q][1] = fmaf(xs[q], d.y, acc[q][1]);
            }
        }
        #pragma unroll
        for (int q = 0; q < NS_BLK; q++)
            *(float2*)(&Hs[q][n0]) = make_float2(acc[q][0], acc[q][1]);
    }
    __syncthreads();

    // OMP: wave's 2 signals, interleaved by the compiler for ILP (indep chains).
    #pragma unroll
    for (int q = 0; q < 2; q++) {
        const int sl = wave * 2 + q;
        const int s = s0 + sl;
        const float xch = Xs[lane][sl];

        float hb[8];
        *(float4*)(&hb[0]) = *(const float4*)(&Hs[sl][lane * 8]);
        *(float4*)(&hb[4]) = *(const float4*)(&Hs[sl][lane * 8 + 4]);

        int I[KS]; float coef[KS];
        omp_body(hb, &Hs[sl][0], G, lane, I, coef);

        int tok[KS]; float cq[KS];
        #pragma unroll
        for (int j = 0; j < KS; j++) {
            float c2 = fminf(fmaxf(coef[j], -2.f), 2.f);
            float bf = (c2 + 2.f) / 4.f * 32.f;
            int bin = (int)rintf(bf);
            bin = bin < 0 ? 0 : (bin > 32 ? 32 : bin);
            cq[j] = -2.f + 0.125f * (float)bin;
            tok[j] = I[j] * NBINS + bin;
        }
        float zq = 0.f;
        #pragma unroll
        for (int j = 0; j < KS; j++)
            zq = fmaf(cq[j], DnT[I[j] * CDIM + lane], zq);

        float diff = zq - xch;
        Hs[sl][lane] = xch + (zq - xch);   // zste overlay (row sl read is done)

        float sq = diff * diff;
        #pragma unroll
        for (int off = 32; off > 0; off >>= 1) sq += __shfl_down(sq, off);
        if (lane == 0) part[s] = sq;
        if (lane < KS) tk[sl][lane] = (float)tok[lane];
    }
    __syncthreads();

    if (t < 128) {   // coalesced zste write: c = t>>1, signals f..f+3
        const int c = t >> 1, f = (t & 1) * 4;
        float4 v;
        v.x = Hs[f + 0][c]; v.y = Hs[f + 1][c];
        v.z = Hs[f + 2][c]; v.w = Hs[f + 3][c];
        *(float4*)(out + (b * CDIM + c) * 1024 + hw0 + f) = v;
    }
    if (t < NS_BLK * KS)   // 32 consecutive token floats
        out[NSIG * CDIM + 1 + s0 * KS + t] = tk[t >> 2][t & 3];
}

__global__ __launch_bounds__(256) void k_final(const float* __restrict__ part,
                                               float* __restrict__ out) {
    __shared__ float red[4];
    const int t = threadIdx.x;
    float sum = 0.f;
    const float4* p4 = (const float4*)part;
    for (int i = t; i < NSIG / 4; i += 256) {
        float4 v = p4[i];
        sum += v.x + v.y + v.z + v.w;
    }
    #pragma unroll
    for (int off = 32; off > 0; off >>= 1) sum += __shfl_down(sum, off);
    if ((t & 63) == 0) red[t >> 6] = sum;
    __syncthreads();
    if (t == 0) {
        float v = (red[0] + red[1] + red[2] + red[3]) / 1048576.f;
        out[NSIG * CDIM] = v + 0.25f * v;
    }
}

extern "C" void kernel_launch(void* const* d_in, const int* in_sizes, int n_in,
                              void* d_out, int out_size, void* d_ws, size_t ws_size,
                              hipStream_t stream) {
    const float* z    = (const float*)d_in[0];
    const float* dict = (const float*)d_in[1];
    float* out  = (float*)d_out;
    float* w    = (float*)d_ws;
    float* Dn   = w + WS_DN;
    float* DnT  = w + WS_DNT;
    float* G    = w + WS_G;
    float* part = w + WS_PART;

    hipLaunchKernelGGL(k_normalize, dim3(N_ATOMS), dim3(CDIM), 0, stream, dict, Dn, DnT);
    hipLaunchKernelGGL(k_gram,      dim3(N_ATOMS), dim3(256),  0, stream, Dn, G);
    hipLaunchKernelGGL(k_fused3,    dim3(NSIG / NS_BLK), dim3(256), 0, stream,
                       z, Dn, DnT, G, part, out);
    hipLaunchKernelGGL(k_final,     dim3(1), dim3(256), 0, stream, part, out);
}